// Round 15
// baseline (281.994 us; speedup 1.0000x reference)
//
#include <hip/hip_runtime.h>
#include <math.h>

#define BN_EPS 1e-5f

typedef __attribute__((ext_vector_type(4))) float f4;
typedef __attribute__((ext_vector_type(4))) int i4v;
typedef __attribute__((ext_vector_type(8))) short short8;
typedef __attribute__((ext_vector_type(4))) float f32x4;
typedef _Float16 half4v __attribute__((ext_vector_type(4)));

__device__ inline unsigned short f2bf(float f) {
    unsigned int u = __builtin_bit_cast(unsigned int, f);
    return (unsigned short)((u + 0x7FFFu + ((u >> 16) & 1u)) >> 16);
}
__device__ inline float blo(int u) { return __builtin_bit_cast(float, (int)(u << 16)); }
__device__ inline float bhi(int u) { return __builtin_bit_cast(float, (int)(u & 0xffff0000)); }
// pack two fp32 -> bf16x2 (round-half-up): 2 int adds + 1 v_perm
__device__ inline int pkbf_fast(float hi, float lo) {
    unsigned uh = __builtin_bit_cast(unsigned, hi) + 0x8000u;
    unsigned ul = __builtin_bit_cast(unsigned, lo) + 0x8000u;
    return (int)__builtin_amdgcn_perm(uh, ul, 0x07060302u);
}

// ---------------- fused weight conversion: all 7 weight tensors (bf16) ----------------
struct CvtSeg { const float* src; unsigned short* dst; int oreal, c, kpad, end; };
struct CvtArgs { CvtSeg s[7]; };

__global__ __launch_bounds__(256)
void cvt_all(CvtArgs a)
{
    int idx = blockIdx.x * 256 + threadIdx.x;
    int base = 0;
    #pragma unroll
    for (int i = 0; i < 7; ++i) {
        if (idx < a.s[i].end) {
            int local = idx - base;
            int kpad = a.s[i].kpad, c = a.s[i].c;
            int o = local / kpad, k = local - o * kpad;
            unsigned short val = 0;
            if (o < a.s[i].oreal && k < 9 * c) {
                int n = k / c, cc = k - n * c;
                val = f2bf(a.s[i].src[(o * c + cc) * 9 + n]);
            }
            a.s[i].dst[local] = val;
            return;
        }
        base = a.s[i].end;
    }
}

// ---------------- layer 1: image in LDS + MFMA, NCHW f32 in -> NHWC bf16 out ----------------
__global__ __launch_bounds__(256)
void conv1_tile(const float* __restrict__ x, const unsigned short* __restrict__ wq,
                const float* __restrict__ bias, const float* __restrict__ g,
                const float* __restrict__ be, const float* __restrict__ m,
                const float* __restrict__ v, unsigned short* __restrict__ out)
{
    __shared__ __align__(16) float img[3072];
    __shared__ __align__(16) unsigned short wt[32 * 40];
    __shared__ float scb[32], shb[32];
    const int tid = threadIdx.x;
    const int b = blockIdx.x >> 2;
    const int qtr = blockIdx.x & 3;
    if (tid < 32) {
        float sc = g[tid] * rsqrtf(v[tid] + BN_EPS);
        scb[tid] = sc;
        shb[tid] = be[tid] - m[tid] * sc + bias[tid] * sc;
    }
    *(ushort4*)&wt[(tid >> 3) * 40 + (tid & 7) * 4] =
        *(const ushort4*)(wq + (tid >> 3) * 32 + (tid & 7) * 4);
    const float* xb = x + (size_t)b * 3072;
    #pragma unroll
    for (int r = 0; r < 3; ++r) {
        int idx = r * 256 + tid;
        *(f4*)&img[idx * 4] = *(const f4*)(xb + idx * 4);
    }
    __syncthreads();
    const int wid = tid >> 6, lane = tid & 63, quad = lane >> 4, m16 = lane & 15;
    short8 af0 = *(const short8*)&wt[m16 * 40 + quad * 8];
    short8 af1 = *(const short8*)&wt[(16 + m16) * 40 + quad * 8];
    #pragma unroll
    for (int it = 0; it < 4; ++it) {
        int pix = qtr * 256 + it * 64 + wid * 16 + m16;
        int i = pix >> 5, j = pix & 31;
        short8 bfrag;
        #pragma unroll
        for (int jj = 0; jj < 8; ++jj) {
            int k = quad * 8 + jj;
            float val = 0.f;
            if (k < 27) {
                int n = k / 3, c = k - n * 3;
                int u = i - 1 + n / 3, vv = j - 1 + n % 3;
                if (u >= 0 && u < 32 && vv >= 0 && vv < 32)
                    val = img[c * 1024 + u * 32 + vv];
            }
            bfrag[jj] = (short)f2bf(val);
        }
        f32x4 a0 = {0.f,0.f,0.f,0.f}, a1 = {0.f,0.f,0.f,0.f};
        a0 = __builtin_amdgcn_mfma_f32_16x16x32_bf16(af0, bfrag, a0, 0, 0, 0);
        a1 = __builtin_amdgcn_mfma_f32_16x16x32_bf16(af1, bfrag, a1, 0, 0, 0);
        unsigned short* op = out + ((size_t)b * 1024 + pix) * 32;
        ushort4 s0, s1;
        #pragma unroll
        for (int rr = 0; rr < 4; ++rr) {
            int o0 = quad * 4 + rr, o1 = 16 + quad * 4 + rr;
            ((unsigned short*)&s0)[rr] = f2bf(fmaxf(fmaf(a0[rr], scb[o0], shb[o0]), 0.f));
            ((unsigned short*)&s1)[rr] = f2bf(fmaxf(fmaf(a1[rr], scb[o1], shb[o1]), 0.f));
        }
        *(ushort4*)(op + quad * 4) = s0;
        *(ushort4*)(op + 16 + quad * 4) = s1;
    }
}

// ---------------- fused deformable layer (slim LDS, L2/L3) ----------------
template<int C, int OREAL, int OPAD, int H, int W, int OH, int OW, int S,
         int MTILE, int OBLK>
__global__ __launch_bounds__(256, 4)
void dconv_fused(const unsigned short* __restrict__ xact,
                 const unsigned short* __restrict__ wp, const float* __restrict__ bp,
                 const unsigned short* __restrict__ wc,
                 const float* __restrict__ g, const float* __restrict__ be,
                 const float* __restrict__ m, const float* __restrict__ v,
                 unsigned short* __restrict__ out)
{
    constexpr int K = C * 9;
    constexpr int KCH = C / 32;
    constexpr int OPB = OPAD / OBLK;
    constexpr int OT = OPB / 64;
    constexpr int ST = MTILE / 16;
    constexpr int PWP = (MTILE >= 32) ? MTILE / 2 : MTILE;
    constexpr int STP = PWP / 16;
    constexpr int CP = C + 8;
    constexpr int GL = C / 8;
    constexpr int NGRP = 256 / GL;
    constexpr int NT = MTILE / NGRP;
    constexpr int OHW = OH * OW;
    constexpr int HWC = H * W * C;
    constexpr int Hp = H + 2, Wpp = W + 2;
    static_assert(MTILE % NGRP == 0 && OPB % 64 == 0 && STP >= 1, "tiling");

    __shared__ __align__(16) unsigned short xo[2][MTILE * CP];
    __shared__ __align__(8) ushort4   tab_p[MTILE][9];
    __shared__ __align__(8) _Float16  tab_h[MTILE][9][4];
    __shared__ _Float16 off_lds[MTILE][20];
    __shared__ int imgb[MTILE];
    __shared__ float scb[OPAD], shb[OPAD];

    const int tid = threadIdx.x;
    const int ob  = blockIdx.x % OBLK;
    const int p0  = (blockIdx.x / OBLK) * MTILE;

    if (tid < MTILE) imgb[tid] = ((p0 + tid) / OHW) * HWC;
    for (int o = tid; o < OREAL; o += 256) {
        float sc = g[o] * rsqrtf(v[o] + BN_EPS);
        scb[o] = sc;
        shb[o] = be[o] - m[o] * sc;
    }
    for (int e = tid; e < MTILE * 9; e += 256) {
        int lp = e / 9, n = e % 9;
        int p = p0 + lp;
        int rem = p % OHW;
        int i = rem / OW, j = rem % OW;
        int u = i * S - 1 + n / 3, vv = j * S - 1 + n % 3;
        bool ok = (u >= 0 && u < H && vv >= 0 && vv < W);
        ushort4 tp;
        tp.x = ok ? (unsigned short)((u * W + vv) * C) : (unsigned short)0;
        tp.y = ok ? (unsigned short)0xFFFF : (unsigned short)0;
        tp.z = 0; tp.w = 0;
        tab_p[lp][n] = tp;
    }
    __syncthreads();

    const int gl = tid % GL, grp = tid / GL;
    const int wid = tid >> 6, lane = tid & 63, quad = lane >> 4, m16 = lane & 15;

    // ---- Phase A: offset conv ----
    {
        const int ogp = wid & 1;
        const int pgp = (MTILE >= 32) ? (wid >> 1) : 0;
        const int obp = ogp * 16;
        const int pbp = pgp * PWP;
        i4v Tp[NT];
        auto issueA = [&](int n) {
            #pragma unroll
            for (int it = 0; it < NT; ++it) {
                const int pix = it * NGRP + grp;
                Tp[it] = *(const i4v*)(xact + imgb[pix] + gl * 8 + (int)tab_p[pix][n].x);
            }
        };
        auto commitA = [&](int n, int buf) {
            #pragma unroll
            for (int it = 0; it < NT; ++it) {
                const int pix = it * NGRP + grp;
                int mask = (int)(short)tab_p[pix][n].y;
                i4v R;
                #pragma unroll
                for (int e2 = 0; e2 < 4; ++e2) R[e2] = Tp[it][e2] & mask;
                *(i4v*)&xo[buf][pix * CP + gl * 8] = R;
            }
        };
        auto loadWp = [&](int n, short8* wf) {
            #pragma unroll
            for (int ch = 0; ch < KCH; ++ch)
                wf[ch] = *(const short8*)(wp + (size_t)(obp + m16) * K
                                          + n * C + ch * 32 + quad * 8);
        };
        f32x4 accp[STP];
        #pragma unroll
        for (int st = 0; st < STP; ++st) accp[st] = (f32x4){0.f, 0.f, 0.f, 0.f};
        short8 wfA[KCH], wfB[KCH];
        issueA(0);
        loadWp(0, wfA);
        commitA(0, 0);
        __syncthreads();
        for (int n = 0; n < 9; ++n) {
            const int cur = n & 1;
            if (n < 8) { issueA(n + 1); loadWp(n + 1, wfB); }
            #pragma unroll
            for (int ch = 0; ch < KCH; ++ch)
                #pragma unroll
                for (int st = 0; st < STP; ++st) {
                    short8 bf = *(const short8*)&xo[cur][(pbp + st * 16 + m16) * CP
                                                        + ch * 32 + quad * 8];
                    accp[st] = __builtin_amdgcn_mfma_f32_16x16x32_bf16(
                        wfA[ch], bf, accp[st], 0, 0, 0);
                }
            if (n < 8) {
                commitA(n + 1, cur ^ 1);
                #pragma unroll
                for (int ch = 0; ch < KCH; ++ch) wfA[ch] = wfB[ch];
            }
            __syncthreads();
        }
        #pragma unroll
        for (int st = 0; st < STP; ++st) {
            int pix = pbp + st * 16 + m16;
            #pragma unroll
            for (int rr = 0; rr < 4; ++rr) {
                int o = obp + quad * 4 + rr;
                if (o < 18) off_lds[pix][o] = (_Float16)(accp[st][rr] + bp[o]);
            }
        }
    }
    __syncthreads();

    // ---- Phase B: bilinear tables ----
    for (int e = tid; e < MTILE * 9; e += 256) {
        int lp = e / 9, n = e % 9;
        int p = p0 + lp;
        int rem = p % OHW;
        int i = rem / OW, j = rem % OW;
        float ox = (float)off_lds[lp][n];
        float oy = (float)off_lds[lp][9 + n];
        float px = (float)(i * S + n / 3) + ox;
        float py = (float)(j * S + n % 3) + oy;
        int qx0 = (int)floorf(px), qy0 = (int)floorf(py);
        int x0 = min(max(qx0, 0), Hp - 1), x1 = min(max(qx0 + 1, 0), Hp - 1);
        int y0 = min(max(qy0, 0), Wpp - 1), y1 = min(max(qy0 + 1, 0), Wpp - 1);
        float pxc = fminf(fmaxf(px, 0.f), (float)(Hp - 1));
        float pyc = fminf(fmaxf(py, 0.f), (float)(Wpp - 1));
        float gx0 = 1.f + ((float)x0 - pxc), gx1 = 1.f - ((float)x1 - pxc);
        float gy0 = 1.f + ((float)y0 - pyc), gy1 = 1.f - ((float)y1 - pyc);
        int u0 = x0 - 1, u1 = x1 - 1, v0 = y0 - 1, v1 = y1 - 1;
        bool k0 = (u0 >= 0 && u0 < H && v0 >= 0 && v0 < W);
        bool k1 = (u1 >= 0 && u1 < H && v1 >= 0 && v1 < W);
        bool k2 = (u0 >= 0 && u0 < H && v1 >= 0 && v1 < W);
        bool k3 = (u1 >= 0 && u1 < H && v0 >= 0 && v0 < W);
        ushort4 tp;
        tp.x = k0 ? (unsigned short)((u0 * W + v0) * C) : (unsigned short)0;
        tp.y = k1 ? (unsigned short)((u1 * W + v1) * C) : (unsigned short)0;
        tp.z = k2 ? (unsigned short)((u0 * W + v1) * C) : (unsigned short)0;
        tp.w = k3 ? (unsigned short)((u1 * W + v0) * C) : (unsigned short)0;
        tab_p[lp][n] = tp;
        half4v hw;
        hw[0] = (_Float16)(k0 ? gx0 * gy0 : 0.f);
        hw[1] = (_Float16)(k1 ? gx1 * gy1 : 0.f);
        hw[2] = (_Float16)(k2 ? gx0 * gy1 : 0.f);
        hw[3] = (_Float16)(k3 ? gx1 * gy0 : 0.f);
        *(half4v*)&tab_h[lp][n][0] = hw;
    }
    __syncthreads();

    // ---- Phase C: deform conv ----
    {
        const int obase = ob * OPB + wid * OT * 16;
        i4v T[NT][4];
        auto issueC = [&](int n) {
            #pragma unroll
            for (int it = 0; it < NT; ++it) {
                const int pix = it * NGRP + grp;
                const unsigned short* xb = xact + imgb[pix] + gl * 8;
                ushort4 tp = tab_p[pix][n];
                T[it][0] = *(const i4v*)(xb + tp.x);
                T[it][1] = *(const i4v*)(xb + tp.y);
                T[it][2] = *(const i4v*)(xb + tp.z);
                T[it][3] = *(const i4v*)(xb + tp.w);
            }
        };
        auto commitC = [&](int n, int buf) {
            #pragma unroll
            for (int it = 0; it < NT; ++it) {
                const int pix = it * NGRP + grp;
                half4v hw = *(const half4v*)&tab_h[pix][n][0];
                float w0 = (float)hw[0], w1 = (float)hw[1];
                float w2 = (float)hw[2], w3 = (float)hw[3];
                i4v R;
                #pragma unroll
                for (int e2 = 0; e2 < 4; ++e2) {
                    float lo = w0 * blo(T[it][0][e2]);
                    lo = fmaf(w1, blo(T[it][1][e2]), lo);
                    lo = fmaf(w2, blo(T[it][2][e2]), lo);
                    lo = fmaf(w3, blo(T[it][3][e2]), lo);
                    float hi = w0 * bhi(T[it][0][e2]);
                    hi = fmaf(w1, bhi(T[it][1][e2]), hi);
                    hi = fmaf(w2, bhi(T[it][2][e2]), hi);
                    hi = fmaf(w3, bhi(T[it][3][e2]), hi);
                    R[e2] = pkbf_fast(hi, lo);
                }
                *(i4v*)&xo[buf][pix * CP + gl * 8] = R;
            }
        };
        auto loadWc = [&](int n, short8 (*wf)[OT]) {
            #pragma unroll
            for (int ch = 0; ch < KCH; ++ch)
                #pragma unroll
                for (int t = 0; t < OT; ++t)
                    wf[ch][t] = *(const short8*)(wc + (size_t)(obase + t * 16 + m16) * K
                                                 + n * C + ch * 32 + quad * 8);
        };

        f32x4 acc[ST][OT];
        #pragma unroll
        for (int st = 0; st < ST; ++st)
            #pragma unroll
            for (int t = 0; t < OT; ++t) acc[st][t] = (f32x4){0.f, 0.f, 0.f, 0.f};

        short8 wfA[KCH][OT], wfB[KCH][OT];
        issueC(0);
        loadWc(0, wfA);
        commitC(0, 0);
        __syncthreads();

        for (int n = 0; n < 9; ++n) {
            const int cur = n & 1;
            if (n < 8) {
                issueC(n + 1);
                loadWc(n + 1, wfB);
            }
            #pragma unroll
            for (int ch = 0; ch < KCH; ++ch)
                #pragma unroll
                for (int st = 0; st < ST; ++st) {
                    short8 bf = *(const short8*)&xo[cur][(st * 16 + m16) * CP
                                                        + ch * 32 + quad * 8];
                    #pragma unroll
                    for (int t = 0; t < OT; ++t)
                        acc[st][t] = __builtin_amdgcn_mfma_f32_16x16x32_bf16(
                            wfA[ch][t], bf, acc[st][t], 0, 0, 0);
                }
            if (n < 8) {
                commitC(n + 1, cur ^ 1);
                #pragma unroll
                for (int ch = 0; ch < KCH; ++ch)
                    #pragma unroll
                    for (int t = 0; t < OT; ++t) wfA[ch][t] = wfB[ch][t];
            }
            __syncthreads();
        }

        #pragma unroll
        for (int st = 0; st < ST; ++st) {
            const int p = p0 + st * 16 + m16;
            #pragma unroll
            for (int t = 0; t < OT; ++t) {
                int o = obase + t * 16 + quad * 4;
                ushort4 s;
                #pragma unroll
                for (int rr = 0; rr < 4; ++rr)
                    ((unsigned short*)&s)[rr] =
                        f2bf(fmaxf(fmaf(acc[st][t][rr], scb[o + rr], shb[o + rr]), 0.f));
                *(ushort4*)(out + (size_t)p * OPAD + o) = s;
            }
        }
    }
}

// ---------------- L4: whole-image-in-LDS fused deform layer (barrier-light) ----------------
// Block = (image, O-half). Image (64 KB) staged to LDS once; offset conv and
// deform gather both read the LDS image directly — no scattered global loads,
// no K-loop barriers (3 barriers total). Tables computed per-lane in registers.
template<int C, int O, int H, int W, int OH, int OW, int S>
__global__ __launch_bounds__(256, 2)
void dconv_img(const unsigned short* __restrict__ xact,
               const unsigned short* __restrict__ wp, const float* __restrict__ bp,
               const unsigned short* __restrict__ wc,
               const float* __restrict__ g, const float* __restrict__ be,
               const float* __restrict__ m, const float* __restrict__ v,
               unsigned short* __restrict__ out)
{
    constexpr int K = C * 9;
    constexpr int KCH = C / 32;
    constexpr int NPIX = OH * OW;        // 64
    constexpr int ST = NPIX / 16;        // 4
    constexpr int HWC = H * W * C;
    constexpr int Hp = H + 2, Wpp = W + 2;

    __shared__ __align__(16) unsigned short img[HWC];
    __shared__ _Float16 off_lds[NPIX][20];
    __shared__ float scb[O], shb[O];

    const int tid = threadIdx.x;
    const int b  = blockIdx.x >> 1;
    const int ob = blockIdx.x & 1;

    const unsigned short* srcim = xact + (size_t)b * HWC;
    #pragma unroll
    for (int it = 0; it < HWC / 2048; ++it) {
        int idx = (it * 256 + tid) * 8;
        *(i4v*)&img[idx] = *(const i4v*)(srcim + idx);
    }
    for (int o = tid; o < O; o += 256) {
        float sc = g[o] * rsqrtf(v[o] + BN_EPS);
        scb[o] = sc;
        shb[o] = be[o] - m[o] * sc;
    }
    __syncthreads();

    const int wid = tid >> 6, lane = tid & 63, quad = lane >> 4, m16 = lane & 15;

    // ---- Phase A: offset conv (each wave: 16 pixels x 32-padded outputs) ----
    {
        const int pl = wid * 16 + m16;
        const int i = pl / OW, j = pl % OW;
        f32x4 accp[2] = {{0.f,0.f,0.f,0.f},{0.f,0.f,0.f,0.f}};
        short8 wfA[KCH][2], wfB[KCH][2];
        auto loadWp = [&](int n, short8 (*wf)[2]) {
            #pragma unroll
            for (int ch = 0; ch < KCH; ++ch)
                #pragma unroll
                for (int t = 0; t < 2; ++t)
                    wf[ch][t] = *(const short8*)(wp + (size_t)(t * 16 + m16) * K
                                                 + n * C + ch * 32 + quad * 8);
        };
        loadWp(0, wfA);
        for (int n = 0; n < 9; ++n) {
            if (n < 8) loadWp(n + 1, wfB);
            int u = i * S - 1 + n / 3, vv = j * S - 1 + n % 3;
            bool ok = (u >= 0 && u < H && vv >= 0 && vv < W);
            int ta = ok ? (u * W + vv) * C : 0;
            int mask = ok ? -1 : 0;
            #pragma unroll
            for (int ch = 0; ch < KCH; ++ch) {
                i4v A = *(const i4v*)&img[ta + ch * 32 + quad * 8];
                i4v R;
                #pragma unroll
                for (int e2 = 0; e2 < 4; ++e2) R[e2] = A[e2] & mask;
                short8 bf = __builtin_bit_cast(short8, R);
                accp[0] = __builtin_amdgcn_mfma_f32_16x16x32_bf16(wfA[ch][0], bf, accp[0], 0, 0, 0);
                accp[1] = __builtin_amdgcn_mfma_f32_16x16x32_bf16(wfA[ch][1], bf, accp[1], 0, 0, 0);
            }
            if (n < 8) {
                #pragma unroll
                for (int ch = 0; ch < KCH; ++ch) {
                    wfA[ch][0] = wfB[ch][0];
                    wfA[ch][1] = wfB[ch][1];
                }
            }
        }
        #pragma unroll
        for (int t = 0; t < 2; ++t)
            #pragma unroll
            for (int rr = 0; rr < 4; ++rr) {
                int o = t * 16 + quad * 4 + rr;
                if (o < 18) off_lds[pl][o] = (_Float16)(accp[t][rr] + bp[o]);
            }
    }
    __syncthreads();

    // ---- Phase C: deform conv (each wave: 16 outputs x all 64 pixels) ----
    {
        const int obase = ob * (O / 2) + wid * 16;
        f32x4 acc[ST];
        #pragma unroll
        for (int st = 0; st < ST; ++st) acc[st] = (f32x4){0.f, 0.f, 0.f, 0.f};
        short8 wfA[KCH], wfB[KCH];
        auto loadWc = [&](int n, short8* wf) {
            #pragma unroll
            for (int ch = 0; ch < KCH; ++ch)
                wf[ch] = *(const short8*)(wc + (size_t)(obase + m16) * K
                                          + n * C + ch * 32 + quad * 8);
        };
        loadWc(0, wfA);
        for (int n = 0; n < 9; ++n) {
            if (n < 8) loadWc(n + 1, wfB);
            #pragma unroll
            for (int st = 0; st < ST; ++st) {
                const int pl = st * 16 + m16;
                const int i = pl / OW, j = pl % OW;
                float ox = (float)off_lds[pl][n];
                float oy = (float)off_lds[pl][9 + n];
                float px = (float)(i * S + n / 3) + ox;
                float py = (float)(j * S + n % 3) + oy;
                int qx0 = (int)floorf(px), qy0 = (int)floorf(py);
                int x0 = min(max(qx0, 0), Hp - 1), x1 = min(max(qx0 + 1, 0), Hp - 1);
                int y0 = min(max(qy0, 0), Wpp - 1), y1 = min(max(qy0 + 1, 0), Wpp - 1);
                float pxc = fminf(fmaxf(px, 0.f), (float)(Hp - 1));
                float pyc = fminf(fmaxf(py, 0.f), (float)(Wpp - 1));
                float gx0 = 1.f + ((float)x0 - pxc), gx1 = 1.f - ((float)x1 - pxc);
                float gy0 = 1.f + ((float)y0 - pyc), gy1 = 1.f - ((float)y1 - pyc);
                int u0 = x0 - 1, u1 = x1 - 1, v0 = y0 - 1, v1 = y1 - 1;
                bool k0 = (u0 >= 0 && u0 < H && v0 >= 0 && v0 < W);
                bool k1 = (u1 >= 0 && u1 < H && v1 >= 0 && v1 < W);
                bool k2 = (u0 >= 0 && u0 < H && v1 >= 0 && v1 < W);
                bool k3 = (u1 >= 0 && u1 < H && v0 >= 0 && v0 < W);
                int t0 = k0 ? (u0 * W + v0) * C : 0;  float w0 = k0 ? gx0 * gy0 : 0.f;
                int t1 = k1 ? (u1 * W + v1) * C : 0;  float w1 = k1 ? gx1 * gy1 : 0.f;
                int t2 = k2 ? (u0 * W + v1) * C : 0;  float w2 = k2 ? gx0 * gy1 : 0.f;
                int t3 = k3 ? (u1 * W + v0) * C : 0;  float w3 = k3 ? gx1 * gy0 : 0.f;
                #pragma unroll
                for (int ch = 0; ch < KCH; ++ch) {
                    const int cb = ch * 32 + quad * 8;
                    i4v A  = *(const i4v*)&img[t0 + cb];
                    i4v Bv = *(const i4v*)&img[t1 + cb];
                    i4v Cv = *(const i4v*)&img[t2 + cb];
                    i4v Dv = *(const i4v*)&img[t3 + cb];
                    i4v R;
                    #pragma unroll
                    for (int e2 = 0; e2 < 4; ++e2) {
                        float lo = w0 * blo(A[e2]);
                        lo = fmaf(w1, blo(Bv[e2]), lo);
                        lo = fmaf(w2, blo(Cv[e2]), lo);
                        lo = fmaf(w3, blo(Dv[e2]), lo);
                        float hi = w0 * bhi(A[e2]);
                        hi = fmaf(w1, bhi(Bv[e2]), hi);
                        hi = fmaf(w2, bhi(Cv[e2]), hi);
                        hi = fmaf(w3, bhi(Dv[e2]), hi);
                        R[e2] = pkbf_fast(hi, lo);
                    }
                    short8 bf = __builtin_bit_cast(short8, R);
                    acc[st] = __builtin_amdgcn_mfma_f32_16x16x32_bf16(wfA[ch], bf, acc[st], 0, 0, 0);
                }
            }
            if (n < 8) {
                #pragma unroll
                for (int ch = 0; ch < KCH; ++ch) wfA[ch] = wfB[ch];
            }
        }
        // epilogue
        #pragma unroll
        for (int st = 0; st < ST; ++st) {
            const int pl = st * 16 + m16;
            int o = obase + quad * 4;
            ushort4 s;
            #pragma unroll
            for (int rr = 0; rr < 4; ++rr)
                ((unsigned short*)&s)[rr] =
                    f2bf(fmaxf(fmaf(acc[st][rr], scb[o + rr], shb[o + rr]), 0.f));
            *(ushort4*)(out + ((size_t)b * NPIX + pl) * O + o) = s;
        }
    }
}

// ---------------- global avg pool (8x8, NHWC bf16) + FC 128->100 ----------------
__global__ __launch_bounds__(128)
void pool_fc(const unsigned short* __restrict__ h4, const float* __restrict__ wcls,
             const float* __restrict__ bcls, float* __restrict__ out)
{
    __shared__ float pool[128];
    int b = blockIdx.x;
    int tid = threadIdx.x;
    const unsigned short* src = h4 + (size_t)b * 8192;
    float s = 0.f;
    #pragma unroll
    for (int t = 0; t < 64; ++t)
        s += __builtin_bit_cast(float, (unsigned)src[t * 128 + tid] << 16);
    pool[tid] = s * (1.f / 64.f);
    __syncthreads();
    if (tid < 100) {
        float acc = bcls[tid];
        const float* wr = wcls + tid * 128;
        #pragma unroll
        for (int c = 0; c < 128; ++c) acc = fmaf(pool[c], wr[c], acc);
        out[(size_t)b * 100 + tid] = acc;
    }
}

extern "C" void kernel_launch(void* const* d_in, const int* in_sizes, int n_in,
                              void* d_out, int out_size, void* d_ws, size_t ws_size,
                              hipStream_t stream)
{
    const float* x    = (const float*)d_in[0];
    const float* w1   = (const float*)d_in[1];
    const float* b1   = (const float*)d_in[2];
    const float* g1   = (const float*)d_in[3];
    const float* be1  = (const float*)d_in[4];
    const float* m1   = (const float*)d_in[5];
    const float* v1   = (const float*)d_in[6];
    const float* wp2  = (const float*)d_in[7];
    const float* bp2  = (const float*)d_in[8];
    const float* wc2  = (const float*)d_in[9];
    const float* g2   = (const float*)d_in[10];
    const float* be2  = (const float*)d_in[11];
    const float* m2   = (const float*)d_in[12];
    const float* v2   = (const float*)d_in[13];
    const float* wp3  = (const float*)d_in[14];
    const float* bp3  = (const float*)d_in[15];
    const float* wc3  = (const float*)d_in[16];
    const float* g3   = (const float*)d_in[17];
    const float* be3  = (const float*)d_in[18];
    const float* m3   = (const float*)d_in[19];
    const float* v3   = (const float*)d_in[20];
    const float* wp4  = (const float*)d_in[21];
    const float* bp4  = (const float*)d_in[22];
    const float* wc4  = (const float*)d_in[23];
    const float* g4   = (const float*)d_in[24];
    const float* be4  = (const float*)d_in[25];
    const float* m4   = (const float*)d_in[26];
    const float* v4   = (const float*)d_in[27];
    const float* wcls = (const float*)d_in[28];
    const float* bcls = (const float*)d_in[29];
    float* out = (float*)d_out;

    unsigned short* h1 = (unsigned short*)d_ws;    // NHWC bf16 256*1024*32
    unsigned short* h2 = h1 + 8388608;             // 256*256*64
    unsigned short* h3 = h2 + 4194304;             // 256*256*128
    unsigned short* h4 = h3 + 8388608;             // 256*64*128
    unsigned short* wc2b = h4 + 2097152;           // 64*288
    unsigned short* wc3b = wc2b + 18432;           // 128*576
    unsigned short* wc4b = wc3b + 73728;           // 128*1152
    unsigned short* wp2b = wc4b + 147456;          // 32*288
    unsigned short* wp3b = wp2b + 9216;            // 32*576
    unsigned short* wp4b = wp3b + 18432;           // 32*1152
    unsigned short* wq1  = wp4b + 36864;           // 32*32
    (void)ws_size; (void)in_sizes; (void)n_in; (void)out_size;

    CvtArgs ca;
    ca.s[0] = { wc2, wc2b, 64, 32, 288, 18432 };
    ca.s[1] = { wc3, wc3b, 128, 64, 576, 92160 };
    ca.s[2] = { wc4, wc4b, 128, 128, 1152, 239616 };
    ca.s[3] = { wp2, wp2b, 18, 32, 288, 248832 };
    ca.s[4] = { wp3, wp3b, 18, 64, 576, 267264 };
    ca.s[5] = { wp4, wp4b, 18, 128, 1152, 304128 };
    ca.s[6] = { w1, wq1, 32, 3, 32, 305152 };
    cvt_all<<<1192, 256, 0, stream>>>(ca);

    // Layer 1
    conv1_tile<<<1024, 256, 0, stream>>>(x, wq1, b1, g1, be1, m1, v1, h1);

    // Layer 2 (fused offset+deform): 32x32 -> 16x16, stride 2, C=32 -> O=64
    dconv_fused<32, 64, 64, 32, 32, 16, 16, 2, 64, 1><<<1024, 256, 0, stream>>>(
        h1, wp2b, bp2, wc2b, g2, be2, m2, v2, h2);

    // Layer 3: 16x16 -> 16x16, stride 1, C=64 -> O=128
    dconv_fused<64, 128, 128, 16, 16, 16, 16, 1, 64, 1><<<1024, 256, 0, stream>>>(
        h2, wp3b, bp3, wc3b, g3, be3, m3, v3, h3);

    // Layer 4: image-in-LDS kernel, 16x16 -> 8x8, stride 2, C=128 -> O=128
    // block = (image, O-half): 512 blocks, 2/CU
    dconv_img<128, 128, 16, 16, 8, 8, 2><<<512, 256, 0, stream>>>(
        h3, wp4b, bp4, wc4b, g4, be4, m4, v4, h4);

    // Pool + FC
    pool_fc<<<256, 128, 0, stream>>>(h4, wcls, bcls, out);
}

// Round 16
// 234.406 us; speedup vs baseline: 1.2030x; 1.2030x over previous
//
#include <hip/hip_runtime.h>
#include <math.h>

#define BN_EPS 1e-5f

typedef __attribute__((ext_vector_type(4))) float f4;
typedef __attribute__((ext_vector_type(4))) int i4v;
typedef __attribute__((ext_vector_type(8))) short short8;
typedef __attribute__((ext_vector_type(4))) float f32x4;

__device__ inline unsigned short f2bf(float f) {
    unsigned int u = __builtin_bit_cast(unsigned int, f);
    return (unsigned short)((u + 0x7FFFu + ((u >> 16) & 1u)) >> 16);
}
__device__ inline float blo(int u) { return __builtin_bit_cast(float, (int)(u << 16)); }
__device__ inline float bhi(int u) { return __builtin_bit_cast(float, (int)(u & 0xffff0000)); }
// pack two fp32 -> bf16x2 (round-half-up): 2 int adds + 1 v_perm
__device__ inline int pkbf_fast(float hi, float lo) {
    unsigned uh = __builtin_bit_cast(unsigned, hi) + 0x8000u;
    unsigned ul = __builtin_bit_cast(unsigned, lo) + 0x8000u;
    return (int)__builtin_amdgcn_perm(uh, ul, 0x07060302u);
}

// ---------------- fused weight conversion: all 7 weight tensors (bf16) ----------------
struct CvtSeg { const float* src; unsigned short* dst; int oreal, c, kpad, end; };
struct CvtArgs { CvtSeg s[7]; };

__global__ __launch_bounds__(256)
void cvt_all(CvtArgs a)
{
    int idx = blockIdx.x * 256 + threadIdx.x;
    int base = 0;
    #pragma unroll
    for (int i = 0; i < 7; ++i) {
        if (idx < a.s[i].end) {
            int local = idx - base;
            int kpad = a.s[i].kpad, c = a.s[i].c;
            int o = local / kpad, k = local - o * kpad;
            unsigned short val = 0;
            if (o < a.s[i].oreal && k < 9 * c) {
                int n = k / c, cc = k - n * c;
                val = f2bf(a.s[i].src[(o * c + cc) * 9 + n]);
            }
            a.s[i].dst[local] = val;
            return;
        }
        base = a.s[i].end;
    }
}

// ---------------- layer 1: image in LDS + MFMA, NCHW f32 in -> NHWC bf16 out ----------------
__global__ __launch_bounds__(256)
void conv1_tile(const float* __restrict__ x, const unsigned short* __restrict__ wq,
                const float* __restrict__ bias, const float* __restrict__ g,
                const float* __restrict__ be, const float* __restrict__ m,
                const float* __restrict__ v, unsigned short* __restrict__ out)
{
    __shared__ __align__(16) float img[3072];
    __shared__ __align__(16) unsigned short wt[32 * 40];
    __shared__ float scb[32], shb[32];
    const int tid = threadIdx.x;
    const int b = blockIdx.x >> 2;
    const int qtr = blockIdx.x & 3;
    if (tid < 32) {
        float sc = g[tid] * rsqrtf(v[tid] + BN_EPS);
        scb[tid] = sc;
        shb[tid] = be[tid] - m[tid] * sc + bias[tid] * sc;
    }
    *(ushort4*)&wt[(tid >> 3) * 40 + (tid & 7) * 4] =
        *(const ushort4*)(wq + (tid >> 3) * 32 + (tid & 7) * 4);
    const float* xb = x + (size_t)b * 3072;
    #pragma unroll
    for (int r = 0; r < 3; ++r) {
        int idx = r * 256 + tid;
        *(f4*)&img[idx * 4] = *(const f4*)(xb + idx * 4);
    }
    __syncthreads();
    const int wid = tid >> 6, lane = tid & 63, quad = lane >> 4, m16 = lane & 15;
    short8 af0 = *(const short8*)&wt[m16 * 40 + quad * 8];
    short8 af1 = *(const short8*)&wt[(16 + m16) * 40 + quad * 8];
    #pragma unroll
    for (int it = 0; it < 4; ++it) {
        int pix = qtr * 256 + it * 64 + wid * 16 + m16;
        int i = pix >> 5, j = pix & 31;
        short8 bfrag;
        #pragma unroll
        for (int jj = 0; jj < 8; ++jj) {
            int k = quad * 8 + jj;
            float val = 0.f;
            if (k < 27) {
                int n = k / 3, c = k - n * 3;
                int u = i - 1 + n / 3, vv = j - 1 + n % 3;
                if (u >= 0 && u < 32 && vv >= 0 && vv < 32)
                    val = img[c * 1024 + u * 32 + vv];
            }
            bfrag[jj] = (short)f2bf(val);
        }
        f32x4 a0 = {0.f,0.f,0.f,0.f}, a1 = {0.f,0.f,0.f,0.f};
        a0 = __builtin_amdgcn_mfma_f32_16x16x32_bf16(af0, bfrag, a0, 0, 0, 0);
        a1 = __builtin_amdgcn_mfma_f32_16x16x32_bf16(af1, bfrag, a1, 0, 0, 0);
        unsigned short* op = out + ((size_t)b * 1024 + pix) * 32;
        ushort4 s0, s1;
        #pragma unroll
        for (int rr = 0; rr < 4; ++rr) {
            int o0 = quad * 4 + rr, o1 = 16 + quad * 4 + rr;
            ((unsigned short*)&s0)[rr] = f2bf(fmaxf(fmaf(a0[rr], scb[o0], shb[o0]), 0.f));
            ((unsigned short*)&s1)[rr] = f2bf(fmaxf(fmaf(a1[rr], scb[o1], shb[o1]), 0.f));
        }
        *(ushort4*)(op + quad * 4) = s0;
        *(ushort4*)(op + 16 + quad * 4) = s1;
    }
}

// ---------------- fully fused deformable layer: offset conv + deform conv + BN + ReLU ----------
// Phase A: offset = conv3x3(x, wp)+bp for this block's MTILE pixels (MFMA GEMM,
//          OPAD=32, 2-way O-split) -> off_lds.  Phase B: bilinear tables from LDS.
//          Phase C: deform GEMM (4-way O-split) with issue->MFMA->commit pipeline.
// Activations bf16 NHWC, k = n*C + c.
template<int C, int OREAL, int OPAD, int H, int W, int OH, int OW, int S, int MTILE>
__global__ __launch_bounds__(256, 3)
void dconv_fused(const unsigned short* __restrict__ xact,
                 const unsigned short* __restrict__ wp, const float* __restrict__ bp,
                 const unsigned short* __restrict__ wc,
                 const float* __restrict__ g, const float* __restrict__ be,
                 const float* __restrict__ m, const float* __restrict__ v,
                 unsigned short* __restrict__ out)
{
    constexpr int K = C * 9;
    constexpr int KCH = C / 32;
    constexpr int OT = OPAD / 64;            // deform: OSPLIT=4, G=1
    constexpr int ST = MTILE / 16;
    constexpr int PWP = MTILE / 2;           // offset: OSPLIT=2
    constexpr int STP = PWP / 16;
    constexpr int CP = C + 8;
    constexpr int GL = C / 8;
    constexpr int NGRP = 256 / GL;
    constexpr int NT = MTILE / NGRP;
    constexpr int OHW = OH * OW;
    constexpr int HWC = H * W * C;
    constexpr int Hp = H + 2, Wpp = W + 2;
    static_assert(MTILE % NGRP == 0 && OPAD % 64 == 0, "tiling");

    __shared__ __align__(16) unsigned short xo[2][MTILE * CP];
    __shared__ __align__(16) i4v tab_i[MTILE][9];
    __shared__ __align__(16) f4  tab_w[MTILE][9];
    __shared__ int tab_o[MTILE][9];
    __shared__ int tab_m[MTILE][9];
    __shared__ float off_lds[MTILE][20];
    __shared__ int imgb[MTILE];
    __shared__ float scb[OPAD], shb[OPAD];

    const int tid = threadIdx.x;
    const int p0 = blockIdx.x * MTILE;

    if (tid < MTILE) imgb[tid] = ((p0 + tid) / OHW) * HWC;
    for (int o = tid; o < OREAL; o += 256) {
        float sc = g[o] * rsqrtf(v[o] + BN_EPS);
        scb[o] = sc;
        shb[o] = be[o] - m[o] * sc;
    }
    // regular 3x3 taps (for the offset conv)
    for (int e = tid; e < MTILE * 9; e += 256) {
        int lp = e / 9, n = e % 9;
        int p = p0 + lp;
        int rem = p % OHW;
        int i = rem / OW, j = rem % OW;
        int u = i * S - 1 + n / 3, vv = j * S - 1 + n % 3;
        bool ok = (u >= 0 && u < H && vv >= 0 && vv < W);
        tab_o[lp][n] = ok ? (u * W + vv) * C : 0;
        tab_m[lp][n] = ok ? -1 : 0;
    }
    __syncthreads();

    const int gl = tid % GL, grp = tid / GL;
    const int wid = tid >> 6, lane = tid & 63, quad = lane >> 4, m16 = lane & 15;

    // ================= Phase A: offset conv (18->pad 32 outputs) =================
    {
        const int ogp = wid & 1, pgp = wid >> 1;
        const int obp = ogp * 16;
        const int pbp = pgp * PWP;
        i4v Tp[NT];
        auto issueA = [&](int n) {
            #pragma unroll
            for (int it = 0; it < NT; ++it) {
                const int pix = it * NGRP + grp;
                Tp[it] = *(const i4v*)(xact + imgb[pix] + gl * 8 + tab_o[pix][n]);
            }
        };
        auto commitA = [&](int n, int buf) {
            #pragma unroll
            for (int it = 0; it < NT; ++it) {
                const int pix = it * NGRP + grp;
                int mask = tab_m[pix][n];
                i4v R;
                #pragma unroll
                for (int e2 = 0; e2 < 4; ++e2) R[e2] = Tp[it][e2] & mask;
                *(i4v*)&xo[buf][pix * CP + gl * 8] = R;
            }
        };
        auto loadWp = [&](int n, short8* wf) {
            #pragma unroll
            for (int ch = 0; ch < KCH; ++ch)
                wf[ch] = *(const short8*)(wp + (size_t)(obp + m16) * K
                                          + n * C + ch * 32 + quad * 8);
        };
        f32x4 accp[STP];
        #pragma unroll
        for (int st = 0; st < STP; ++st) accp[st] = (f32x4){0.f, 0.f, 0.f, 0.f};
        short8 wfA[KCH], wfB[KCH];
        issueA(0);
        loadWp(0, wfA);
        commitA(0, 0);
        __syncthreads();
        for (int n = 0; n < 9; ++n) {
            const int cur = n & 1;
            if (n < 8) { issueA(n + 1); loadWp(n + 1, wfB); }
            #pragma unroll
            for (int ch = 0; ch < KCH; ++ch)
                #pragma unroll
                for (int st = 0; st < STP; ++st) {
                    short8 bf = *(const short8*)&xo[cur][(pbp + st * 16 + m16) * CP
                                                        + ch * 32 + quad * 8];
                    accp[st] = __builtin_amdgcn_mfma_f32_16x16x32_bf16(
                        wfA[ch], bf, accp[st], 0, 0, 0);
                }
            if (n < 8) {
                commitA(n + 1, cur ^ 1);
                #pragma unroll
                for (int ch = 0; ch < KCH; ++ch) wfA[ch] = wfB[ch];
            }
            __syncthreads();
        }
        #pragma unroll
        for (int st = 0; st < STP; ++st) {
            int pix = pbp + st * 16 + m16;
            #pragma unroll
            for (int rr = 0; rr < 4; ++rr) {
                int o = obp + quad * 4 + rr;
                if (o < 18) off_lds[pix][o] = accp[st][rr] + bp[o];
            }
        }
    }
    __syncthreads();

    // ================= Phase B: bilinear tables from LDS offsets =================
    for (int e = tid; e < MTILE * 9; e += 256) {
        int lp = e / 9, n = e % 9;
        int p = p0 + lp;
        int rem = p % OHW;
        int i = rem / OW, j = rem % OW;
        float ox = off_lds[lp][n];
        float oy = off_lds[lp][9 + n];
        float px = (float)(i * S + n / 3) + ox;
        float py = (float)(j * S + n % 3) + oy;
        int qx0 = (int)floorf(px), qy0 = (int)floorf(py);
        int x0 = min(max(qx0, 0), Hp - 1), x1 = min(max(qx0 + 1, 0), Hp - 1);
        int y0 = min(max(qy0, 0), Wpp - 1), y1 = min(max(qy0 + 1, 0), Wpp - 1);
        float pxc = fminf(fmaxf(px, 0.f), (float)(Hp - 1));
        float pyc = fminf(fmaxf(py, 0.f), (float)(Wpp - 1));
        float gx0 = 1.f + ((float)x0 - pxc), gx1 = 1.f - ((float)x1 - pxc);
        float gy0 = 1.f + ((float)y0 - pyc), gy1 = 1.f - ((float)y1 - pyc);
        int u0 = x0 - 1, u1 = x1 - 1, v0 = y0 - 1, v1 = y1 - 1;
        bool k0 = (u0 >= 0 && u0 < H && v0 >= 0 && v0 < W);
        bool k1 = (u1 >= 0 && u1 < H && v1 >= 0 && v1 < W);
        bool k2 = (u0 >= 0 && u0 < H && v1 >= 0 && v1 < W);
        bool k3 = (u1 >= 0 && u1 < H && v0 >= 0 && v0 < W);
        i4v ti; f4 tw;
        ti[0] = k0 ? (u0 * W + v0) * C : 0;  tw[0] = k0 ? gx0 * gy0 : 0.f;
        ti[1] = k1 ? (u1 * W + v1) * C : 0;  tw[1] = k1 ? gx1 * gy1 : 0.f;
        ti[2] = k2 ? (u0 * W + v1) * C : 0;  tw[2] = k2 ? gx0 * gy1 : 0.f;
        ti[3] = k3 ? (u1 * W + v0) * C : 0;  tw[3] = k3 ? gx1 * gy0 : 0.f;
        tab_i[lp][n] = ti;
        tab_w[lp][n] = tw;
    }
    __syncthreads();

    // ================= Phase C: deform conv =================
    {
        const int obase = wid * OT * 16;     // OSPLIT=4, all waves share all pixels
        i4v T[NT][4];
        auto issueC = [&](int n) {
            #pragma unroll
            for (int it = 0; it < NT; ++it) {
                const int pix = it * NGRP + grp;
                const unsigned short* xb = xact + imgb[pix] + gl * 8;
                i4v ti = tab_i[pix][n];
                T[it][0] = *(const i4v*)(xb + ti[0]);
                T[it][1] = *(const i4v*)(xb + ti[1]);
                T[it][2] = *(const i4v*)(xb + ti[2]);
                T[it][3] = *(const i4v*)(xb + ti[3]);
            }
        };
        auto commitC = [&](int n, int buf) {
            #pragma unroll
            for (int it = 0; it < NT; ++it) {
                const int pix = it * NGRP + grp;
                f4 tw = tab_w[pix][n];
                i4v R;
                #pragma unroll
                for (int e2 = 0; e2 < 4; ++e2) {
                    float lo = tw[0] * blo(T[it][0][e2]);
                    lo = fmaf(tw[1], blo(T[it][1][e2]), lo);
                    lo = fmaf(tw[2], blo(T[it][2][e2]), lo);
                    lo = fmaf(tw[3], blo(T[it][3][e2]), lo);
                    float hi = tw[0] * bhi(T[it][0][e2]);
                    hi = fmaf(tw[1], bhi(T[it][1][e2]), hi);
                    hi = fmaf(tw[2], bhi(T[it][2][e2]), hi);
                    hi = fmaf(tw[3], bhi(T[it][3][e2]), hi);
                    R[e2] = pkbf_fast(hi, lo);
                }
                *(i4v*)&xo[buf][pix * CP + gl * 8] = R;
            }
        };
        auto loadWc = [&](int n, short8 (*wf)[OT]) {
            #pragma unroll
            for (int ch = 0; ch < KCH; ++ch)
                #pragma unroll
                for (int t = 0; t < OT; ++t)
                    wf[ch][t] = *(const short8*)(wc + (size_t)(obase + t * 16 + m16) * K
                                                 + n * C + ch * 32 + quad * 8);
        };

        f32x4 acc[ST][OT];
        #pragma unroll
        for (int st = 0; st < ST; ++st)
            #pragma unroll
            for (int t = 0; t < OT; ++t) acc[st][t] = (f32x4){0.f, 0.f, 0.f, 0.f};

        short8 wfA[KCH][OT], wfB[KCH][OT];
        issueC(0);
        loadWc(0, wfA);
        commitC(0, 0);
        __syncthreads();

        for (int n = 0; n < 9; ++n) {
            const int cur = n & 1;
            if (n < 8) {
                issueC(n + 1);
                loadWc(n + 1, wfB);
            }
            #pragma unroll
            for (int ch = 0; ch < KCH; ++ch)
                #pragma unroll
                for (int st = 0; st < ST; ++st) {
                    short8 bf = *(const short8*)&xo[cur][(st * 16 + m16) * CP
                                                        + ch * 32 + quad * 8];
                    #pragma unroll
                    for (int t = 0; t < OT; ++t)
                        acc[st][t] = __builtin_amdgcn_mfma_f32_16x16x32_bf16(
                            wfA[ch][t], bf, acc[st][t], 0, 0, 0);
                }
            if (n < 8) {
                commitC(n + 1, cur ^ 1);
                #pragma unroll
                for (int ch = 0; ch < KCH; ++ch)
                    #pragma unroll
                    for (int t = 0; t < OT; ++t) wfA[ch][t] = wfB[ch][t];
            }
            __syncthreads();
        }

        // epilogue: BN + ReLU, NHWC bf16
        #pragma unroll
        for (int st = 0; st < ST; ++st) {
            const int p = p0 + st * 16 + m16;
            #pragma unroll
            for (int t = 0; t < OT; ++t) {
                int o = obase + t * 16 + quad * 4;
                ushort4 s;
                #pragma unroll
                for (int rr = 0; rr < 4; ++rr)
                    ((unsigned short*)&s)[rr] =
                        f2bf(fmaxf(fmaf(acc[st][t][rr], scb[o + rr], shb[o + rr]), 0.f));
                *(ushort4*)(out + (size_t)p * OPAD + o) = s;
            }
        }
    }
}

// ---------------- global avg pool (8x8, NHWC bf16) + FC 128->100 ----------------
__global__ __launch_bounds__(128)
void pool_fc(const unsigned short* __restrict__ h4, const float* __restrict__ wcls,
             const float* __restrict__ bcls, float* __restrict__ out)
{
    __shared__ float pool[128];
    int b = blockIdx.x;
    int tid = threadIdx.x;
    const unsigned short* src = h4 + (size_t)b * 8192;
    float s = 0.f;
    #pragma unroll
    for (int t = 0; t < 64; ++t)
        s += __builtin_bit_cast(float, (unsigned)src[t * 128 + tid] << 16);
    pool[tid] = s * (1.f / 64.f);
    __syncthreads();
    if (tid < 100) {
        float acc = bcls[tid];
        const float* wr = wcls + tid * 128;
        #pragma unroll
        for (int c = 0; c < 128; ++c) acc = fmaf(pool[c], wr[c], acc);
        out[(size_t)b * 100 + tid] = acc;
    }
}

extern "C" void kernel_launch(void* const* d_in, const int* in_sizes, int n_in,
                              void* d_out, int out_size, void* d_ws, size_t ws_size,
                              hipStream_t stream)
{
    const float* x    = (const float*)d_in[0];
    const float* w1   = (const float*)d_in[1];
    const float* b1   = (const float*)d_in[2];
    const float* g1   = (const float*)d_in[3];
    const float* be1  = (const float*)d_in[4];
    const float* m1   = (const float*)d_in[5];
    const float* v1   = (const float*)d_in[6];
    const float* wp2  = (const float*)d_in[7];
    const float* bp2  = (const float*)d_in[8];
    const float* wc2  = (const float*)d_in[9];
    const float* g2   = (const float*)d_in[10];
    const float* be2  = (const float*)d_in[11];
    const float* m2   = (const float*)d_in[12];
    const float* v2   = (const float*)d_in[13];
    const float* wp3  = (const float*)d_in[14];
    const float* bp3  = (const float*)d_in[15];
    const float* wc3  = (const float*)d_in[16];
    const float* g3   = (const float*)d_in[17];
    const float* be3  = (const float*)d_in[18];
    const float* m3   = (const float*)d_in[19];
    const float* v3   = (const float*)d_in[20];
    const float* wp4  = (const float*)d_in[21];
    const float* bp4  = (const float*)d_in[22];
    const float* wc4  = (const float*)d_in[23];
    const float* g4   = (const float*)d_in[24];
    const float* be4  = (const float*)d_in[25];
    const float* m4   = (const float*)d_in[26];
    const float* v4   = (const float*)d_in[27];
    const float* wcls = (const float*)d_in[28];
    const float* bcls = (const float*)d_in[29];
    float* out = (float*)d_out;

    unsigned short* h1 = (unsigned short*)d_ws;    // NHWC bf16 256*1024*32
    unsigned short* h2 = h1 + 8388608;             // 256*256*64
    unsigned short* h3 = h2 + 4194304;             // 256*256*128
    unsigned short* h4 = h3 + 8388608;             // 256*64*128
    unsigned short* wc2b = h4 + 2097152;           // 64*288
    unsigned short* wc3b = wc2b + 18432;           // 128*576
    unsigned short* wc4b = wc3b + 73728;           // 128*1152
    unsigned short* wp2b = wc4b + 147456;          // 32*288
    unsigned short* wp3b = wp2b + 9216;            // 32*576
    unsigned short* wp4b = wp3b + 18432;           // 32*1152
    unsigned short* wq1  = wp4b + 36864;           // 32*32
    (void)ws_size; (void)in_sizes; (void)n_in; (void)out_size;

    CvtArgs ca;
    ca.s[0] = { wc2, wc2b, 64, 32, 288, 18432 };
    ca.s[1] = { wc3, wc3b, 128, 64, 576, 92160 };
    ca.s[2] = { wc4, wc4b, 128, 128, 1152, 239616 };
    ca.s[3] = { wp2, wp2b, 18, 32, 288, 248832 };
    ca.s[4] = { wp3, wp3b, 18, 64, 576, 267264 };
    ca.s[5] = { wp4, wp4b, 18, 128, 1152, 304128 };
    ca.s[6] = { w1, wq1, 32, 3, 32, 305152 };
    cvt_all<<<1192, 256, 0, stream>>>(ca);

    // Layer 1
    conv1_tile<<<1024, 256, 0, stream>>>(x, wq1, b1, g1, be1, m1, v1, h1);

    // Layer 2 (fused offset+deform): 32x32 -> 16x16, stride 2, C=32 -> O=64
    dconv_fused<32, 64, 64, 32, 32, 16, 16, 2, 64><<<1024, 256, 0, stream>>>(
        h1, wp2b, bp2, wc2b, g2, be2, m2, v2, h2);

    // Layer 3: 16x16 -> 16x16, stride 1, C=64 -> O=128
    dconv_fused<64, 128, 128, 16, 16, 16, 16, 1, 64><<<1024, 256, 0, stream>>>(
        h2, wp3b, bp3, wc3b, g3, be3, m3, v3, h3);

    // Layer 4: 16x16 -> 8x8, stride 2, C=128 -> O=128
    dconv_fused<128, 128, 128, 16, 16, 8, 8, 2, 32><<<512, 256, 0, stream>>>(
        h3, wp4b, bp4, wc4b, g4, be4, m4, v4, h4);

    // Pool + FC
    pool_fc<<<256, 128, 0, stream>>>(h4, wcls, bcls, out);
}

// Round 17
// 228.399 us; speedup vs baseline: 1.2347x; 1.0263x over previous
//
#include <hip/hip_runtime.h>
#include <math.h>

#define BN_EPS 1e-5f

typedef __attribute__((ext_vector_type(4))) float f4;
typedef __attribute__((ext_vector_type(4))) int i4v;
typedef __attribute__((ext_vector_type(8))) short short8;
typedef __attribute__((ext_vector_type(4))) float f32x4;
typedef _Float16 half4v __attribute__((ext_vector_type(4)));

__device__ inline unsigned short f2bf(float f) {
    unsigned int u = __builtin_bit_cast(unsigned int, f);
    return (unsigned short)((u + 0x7FFFu + ((u >> 16) & 1u)) >> 16);
}
__device__ inline float blo(int u) { return __builtin_bit_cast(float, (int)(u << 16)); }
__device__ inline float bhi(int u) { return __builtin_bit_cast(float, (int)(u & 0xffff0000)); }
// pack two fp32 -> bf16x2 (round-half-up): 2 int adds + 1 v_perm
__device__ inline int pkbf_fast(float hi, float lo) {
    unsigned uh = __builtin_bit_cast(unsigned, hi) + 0x8000u;
    unsigned ul = __builtin_bit_cast(unsigned, lo) + 0x8000u;
    return (int)__builtin_amdgcn_perm(uh, ul, 0x07060302u);
}

// ---------------- fused weight conversion: all 7 weight tensors (bf16) ----------------
struct CvtSeg { const float* src; unsigned short* dst; int oreal, c, kpad, end; };
struct CvtArgs { CvtSeg s[7]; };

__global__ __launch_bounds__(256)
void cvt_all(CvtArgs a)
{
    int idx = blockIdx.x * 256 + threadIdx.x;
    int base = 0;
    #pragma unroll
    for (int i = 0; i < 7; ++i) {
        if (idx < a.s[i].end) {
            int local = idx - base;
            int kpad = a.s[i].kpad, c = a.s[i].c;
            int o = local / kpad, k = local - o * kpad;
            unsigned short val = 0;
            if (o < a.s[i].oreal && k < 9 * c) {
                int n = k / c, cc = k - n * c;
                val = f2bf(a.s[i].src[(o * c + cc) * 9 + n]);
            }
            a.s[i].dst[local] = val;
            return;
        }
        base = a.s[i].end;
    }
}

// ---------------- layer 1: image in LDS + MFMA, NCHW f32 in -> NHWC bf16 out ----------------
__global__ __launch_bounds__(256)
void conv1_tile(const float* __restrict__ x, const unsigned short* __restrict__ wq,
                const float* __restrict__ bias, const float* __restrict__ g,
                const float* __restrict__ be, const float* __restrict__ m,
                const float* __restrict__ v, unsigned short* __restrict__ out)
{
    __shared__ __align__(16) float img[3072];
    __shared__ __align__(16) unsigned short wt[32 * 40];
    __shared__ float scb[32], shb[32];
    const int tid = threadIdx.x;
    const int b = blockIdx.x >> 2;
    const int qtr = blockIdx.x & 3;
    if (tid < 32) {
        float sc = g[tid] * rsqrtf(v[tid] + BN_EPS);
        scb[tid] = sc;
        shb[tid] = be[tid] - m[tid] * sc + bias[tid] * sc;
    }
    *(ushort4*)&wt[(tid >> 3) * 40 + (tid & 7) * 4] =
        *(const ushort4*)(wq + (tid >> 3) * 32 + (tid & 7) * 4);
    const float* xb = x + (size_t)b * 3072;
    #pragma unroll
    for (int r = 0; r < 3; ++r) {
        int idx = r * 256 + tid;
        *(f4*)&img[idx * 4] = *(const f4*)(xb + idx * 4);
    }
    __syncthreads();
    const int wid = tid >> 6, lane = tid & 63, quad = lane >> 4, m16 = lane & 15;
    short8 af0 = *(const short8*)&wt[m16 * 40 + quad * 8];
    short8 af1 = *(const short8*)&wt[(16 + m16) * 40 + quad * 8];
    #pragma unroll
    for (int it = 0; it < 4; ++it) {
        int pix = qtr * 256 + it * 64 + wid * 16 + m16;
        int i = pix >> 5, j = pix & 31;
        short8 bfrag;
        #pragma unroll
        for (int jj = 0; jj < 8; ++jj) {
            int k = quad * 8 + jj;
            float val = 0.f;
            if (k < 27) {
                int n = k / 3, c = k - n * 3;
                int u = i - 1 + n / 3, vv = j - 1 + n % 3;
                if (u >= 0 && u < 32 && vv >= 0 && vv < 32)
                    val = img[c * 1024 + u * 32 + vv];
            }
            bfrag[jj] = (short)f2bf(val);
        }
        f32x4 a0 = {0.f,0.f,0.f,0.f}, a1 = {0.f,0.f,0.f,0.f};
        a0 = __builtin_amdgcn_mfma_f32_16x16x32_bf16(af0, bfrag, a0, 0, 0, 0);
        a1 = __builtin_amdgcn_mfma_f32_16x16x32_bf16(af1, bfrag, a1, 0, 0, 0);
        unsigned short* op = out + ((size_t)b * 1024 + pix) * 32;
        ushort4 s0, s1;
        #pragma unroll
        for (int rr = 0; rr < 4; ++rr) {
            int o0 = quad * 4 + rr, o1 = 16 + quad * 4 + rr;
            ((unsigned short*)&s0)[rr] = f2bf(fmaxf(fmaf(a0[rr], scb[o0], shb[o0]), 0.f));
            ((unsigned short*)&s1)[rr] = f2bf(fmaxf(fmaf(a1[rr], scb[o1], shb[o1]), 0.f));
        }
        *(ushort4*)(op + quad * 4) = s0;
        *(ushort4*)(op + 16 + quad * 4) = s1;
    }
}

// ---------------- slim-LDS fused deformable layer (L2/L3): compressed tables ----------------
template<int C, int OREAL, int OPAD, int H, int W, int OH, int OW, int S, int MTILE>
__global__ __launch_bounds__(256, 4)
void dconv_slim(const unsigned short* __restrict__ xact,
                const unsigned short* __restrict__ wp, const float* __restrict__ bp,
                const unsigned short* __restrict__ wc,
                const float* __restrict__ g, const float* __restrict__ be,
                const float* __restrict__ m, const float* __restrict__ v,
                unsigned short* __restrict__ out)
{
    constexpr int K = C * 9;
    constexpr int KCH = C / 32;
    constexpr int OT = OPAD / 64;
    constexpr int ST = MTILE / 16;
    constexpr int PWP = MTILE / 2;
    constexpr int STP = PWP / 16;
    constexpr int CP = C + 8;
    constexpr int GL = C / 8;
    constexpr int NGRP = 256 / GL;
    constexpr int NT = MTILE / NGRP;
    constexpr int OHW = OH * OW;
    constexpr int HWC = H * W * C;
    constexpr int Hp = H + 2, Wpp = W + 2;
    static_assert(MTILE % NGRP == 0 && OPAD % 64 == 0 && STP >= 1, "tiling");

    __shared__ __align__(16) unsigned short xo[2][MTILE * CP];
    __shared__ __align__(8) ushort4   tab_p[MTILE][9];   // A: {off,mask}; C: 4 tap offsets
    __shared__ __align__(8) _Float16  tab_h[MTILE][9][4];// C: 4 bilinear weights (fp16)
    __shared__ _Float16 off_lds[MTILE][20];
    __shared__ int imgb[MTILE];
    __shared__ float scb[OPAD], shb[OPAD];

    const int tid = threadIdx.x;
    const int p0 = blockIdx.x * MTILE;

    if (tid < MTILE) imgb[tid] = ((p0 + tid) / OHW) * HWC;
    for (int o = tid; o < OREAL; o += 256) {
        float sc = g[o] * rsqrtf(v[o] + BN_EPS);
        scb[o] = sc;
        shb[o] = be[o] - m[o] * sc;
    }
    for (int e = tid; e < MTILE * 9; e += 256) {
        int lp = e / 9, n = e % 9;
        int p = p0 + lp;
        int rem = p % OHW;
        int i = rem / OW, j = rem % OW;
        int u = i * S - 1 + n / 3, vv = j * S - 1 + n % 3;
        bool ok = (u >= 0 && u < H && vv >= 0 && vv < W);
        ushort4 tp;
        tp.x = ok ? (unsigned short)((u * W + vv) * C) : (unsigned short)0;
        tp.y = ok ? (unsigned short)0xFFFF : (unsigned short)0;
        tp.z = 0; tp.w = 0;
        tab_p[lp][n] = tp;
    }
    __syncthreads();

    const int gl = tid % GL, grp = tid / GL;
    const int wid = tid >> 6, lane = tid & 63, quad = lane >> 4, m16 = lane & 15;

    // ---- Phase A: offset conv (18 -> pad 32 outputs) ----
    {
        const int ogp = wid & 1;
        const int pgp = wid >> 1;
        const int obp = ogp * 16;
        const int pbp = pgp * PWP;
        i4v Tp[NT];
        auto issueA = [&](int n) {
            #pragma unroll
            for (int it = 0; it < NT; ++it) {
                const int pix = it * NGRP + grp;
                Tp[it] = *(const i4v*)(xact + imgb[pix] + gl * 8 + (int)tab_p[pix][n].x);
            }
        };
        auto commitA = [&](int n, int buf) {
            #pragma unroll
            for (int it = 0; it < NT; ++it) {
                const int pix = it * NGRP + grp;
                int mask = (int)(short)tab_p[pix][n].y;
                i4v R;
                #pragma unroll
                for (int e2 = 0; e2 < 4; ++e2) R[e2] = Tp[it][e2] & mask;
                *(i4v*)&xo[buf][pix * CP + gl * 8] = R;
            }
        };
        auto loadWp = [&](int n, short8* wf) {
            #pragma unroll
            for (int ch = 0; ch < KCH; ++ch)
                wf[ch] = *(const short8*)(wp + (size_t)(obp + m16) * K
                                          + n * C + ch * 32 + quad * 8);
        };
        f32x4 accp[STP];
        #pragma unroll
        for (int st = 0; st < STP; ++st) accp[st] = (f32x4){0.f, 0.f, 0.f, 0.f};
        short8 wfA[KCH], wfB[KCH];
        issueA(0);
        loadWp(0, wfA);
        commitA(0, 0);
        __syncthreads();
        for (int n = 0; n < 9; ++n) {
            const int cur = n & 1;
            if (n < 8) { issueA(n + 1); loadWp(n + 1, wfB); }
            #pragma unroll
            for (int ch = 0; ch < KCH; ++ch)
                #pragma unroll
                for (int st = 0; st < STP; ++st) {
                    short8 bf = *(const short8*)&xo[cur][(pbp + st * 16 + m16) * CP
                                                        + ch * 32 + quad * 8];
                    accp[st] = __builtin_amdgcn_mfma_f32_16x16x32_bf16(
                        wfA[ch], bf, accp[st], 0, 0, 0);
                }
            if (n < 8) {
                commitA(n + 1, cur ^ 1);
                #pragma unroll
                for (int ch = 0; ch < KCH; ++ch) wfA[ch] = wfB[ch];
            }
            __syncthreads();
        }
        #pragma unroll
        for (int st = 0; st < STP; ++st) {
            int pix = pbp + st * 16 + m16;
            #pragma unroll
            for (int rr = 0; rr < 4; ++rr) {
                int o = obp + quad * 4 + rr;
                if (o < 18) off_lds[pix][o] = (_Float16)(accp[st][rr] + bp[o]);
            }
        }
    }
    __syncthreads();

    // ---- Phase B: bilinear tables (overwrites tab_p) ----
    for (int e = tid; e < MTILE * 9; e += 256) {
        int lp = e / 9, n = e % 9;
        int p = p0 + lp;
        int rem = p % OHW;
        int i = rem / OW, j = rem % OW;
        float ox = (float)off_lds[lp][n];
        float oy = (float)off_lds[lp][9 + n];
        float px = (float)(i * S + n / 3) + ox;
        float py = (float)(j * S + n % 3) + oy;
        int qx0 = (int)floorf(px), qy0 = (int)floorf(py);
        int x0 = min(max(qx0, 0), Hp - 1), x1 = min(max(qx0 + 1, 0), Hp - 1);
        int y0 = min(max(qy0, 0), Wpp - 1), y1 = min(max(qy0 + 1, 0), Wpp - 1);
        float pxc = fminf(fmaxf(px, 0.f), (float)(Hp - 1));
        float pyc = fminf(fmaxf(py, 0.f), (float)(Wpp - 1));
        float gx0 = 1.f + ((float)x0 - pxc), gx1 = 1.f - ((float)x1 - pxc);
        float gy0 = 1.f + ((float)y0 - pyc), gy1 = 1.f - ((float)y1 - pyc);
        int u0 = x0 - 1, u1 = x1 - 1, v0 = y0 - 1, v1 = y1 - 1;
        bool k0 = (u0 >= 0 && u0 < H && v0 >= 0 && v0 < W);
        bool k1 = (u1 >= 0 && u1 < H && v1 >= 0 && v1 < W);
        bool k2 = (u0 >= 0 && u0 < H && v1 >= 0 && v1 < W);
        bool k3 = (u1 >= 0 && u1 < H && v0 >= 0 && v0 < W);
        ushort4 tp;
        tp.x = k0 ? (unsigned short)((u0 * W + v0) * C) : (unsigned short)0;
        tp.y = k1 ? (unsigned short)((u1 * W + v1) * C) : (unsigned short)0;
        tp.z = k2 ? (unsigned short)((u0 * W + v1) * C) : (unsigned short)0;
        tp.w = k3 ? (unsigned short)((u1 * W + v0) * C) : (unsigned short)0;
        tab_p[lp][n] = tp;
        half4v hw;
        hw[0] = (_Float16)(k0 ? gx0 * gy0 : 0.f);
        hw[1] = (_Float16)(k1 ? gx1 * gy1 : 0.f);
        hw[2] = (_Float16)(k2 ? gx0 * gy1 : 0.f);
        hw[3] = (_Float16)(k3 ? gx1 * gy0 : 0.f);
        *(half4v*)&tab_h[lp][n][0] = hw;
    }
    __syncthreads();

    // ---- Phase C: deform conv (OSPLIT=4) ----
    {
        const int obase = wid * OT * 16;
        i4v T[NT][4];
        auto issueC = [&](int n) {
            #pragma unroll
            for (int it = 0; it < NT; ++it) {
                const int pix = it * NGRP + grp;
                const unsigned short* xb = xact + imgb[pix] + gl * 8;
                ushort4 tp = tab_p[pix][n];
                T[it][0] = *(const i4v*)(xb + tp.x);
                T[it][1] = *(const i4v*)(xb + tp.y);
                T[it][2] = *(const i4v*)(xb + tp.z);
                T[it][3] = *(const i4v*)(xb + tp.w);
            }
        };
        auto commitC = [&](int n, int buf) {
            #pragma unroll
            for (int it = 0; it < NT; ++it) {
                const int pix = it * NGRP + grp;
                half4v hw = *(const half4v*)&tab_h[pix][n][0];
                float w0 = (float)hw[0], w1 = (float)hw[1];
                float w2 = (float)hw[2], w3 = (float)hw[3];
                i4v R;
                #pragma unroll
                for (int e2 = 0; e2 < 4; ++e2) {
                    float lo = w0 * blo(T[it][0][e2]);
                    lo = fmaf(w1, blo(T[it][1][e2]), lo);
                    lo = fmaf(w2, blo(T[it][2][e2]), lo);
                    lo = fmaf(w3, blo(T[it][3][e2]), lo);
                    float hi = w0 * bhi(T[it][0][e2]);
                    hi = fmaf(w1, bhi(T[it][1][e2]), hi);
                    hi = fmaf(w2, bhi(T[it][2][e2]), hi);
                    hi = fmaf(w3, bhi(T[it][3][e2]), hi);
                    R[e2] = pkbf_fast(hi, lo);
                }
                *(i4v*)&xo[buf][pix * CP + gl * 8] = R;
            }
        };
        auto loadWc = [&](int n, short8 (*wf)[OT]) {
            #pragma unroll
            for (int ch = 0; ch < KCH; ++ch)
                #pragma unroll
                for (int t = 0; t < OT; ++t)
                    wf[ch][t] = *(const short8*)(wc + (size_t)(obase + t * 16 + m16) * K
                                                 + n * C + ch * 32 + quad * 8);
        };

        f32x4 acc[ST][OT];
        #pragma unroll
        for (int st = 0; st < ST; ++st)
            #pragma unroll
            for (int t = 0; t < OT; ++t) acc[st][t] = (f32x4){0.f, 0.f, 0.f, 0.f};

        short8 wfA[KCH][OT], wfB[KCH][OT];
        issueC(0);
        loadWc(0, wfA);
        commitC(0, 0);
        __syncthreads();

        for (int n = 0; n < 9; ++n) {
            const int cur = n & 1;
            if (n < 8) {
                issueC(n + 1);
                loadWc(n + 1, wfB);
            }
            #pragma unroll
            for (int ch = 0; ch < KCH; ++ch)
                #pragma unroll
                for (int st = 0; st < ST; ++st) {
                    short8 bf = *(const short8*)&xo[cur][(st * 16 + m16) * CP
                                                        + ch * 32 + quad * 8];
                    #pragma unroll
                    for (int t = 0; t < OT; ++t)
                        acc[st][t] = __builtin_amdgcn_mfma_f32_16x16x32_bf16(
                            wfA[ch][t], bf, acc[st][t], 0, 0, 0);
                }
            if (n < 8) {
                commitC(n + 1, cur ^ 1);
                #pragma unroll
                for (int ch = 0; ch < KCH; ++ch)
                    #pragma unroll
                    for (int t = 0; t < OT; ++t) wfA[ch][t] = wfB[ch][t];
            }
            __syncthreads();
        }

        #pragma unroll
        for (int st = 0; st < ST; ++st) {
            const int p = p0 + st * 16 + m16;
            #pragma unroll
            for (int t = 0; t < OT; ++t) {
                int o = obase + t * 16 + quad * 4;
                ushort4 s;
                #pragma unroll
                for (int rr = 0; rr < 4; ++rr)
                    ((unsigned short*)&s)[rr] =
                        f2bf(fmaxf(fmaf(acc[st][t][rr], scb[o + rr], shb[o + rr]), 0.f));
                *(ushort4*)(out + (size_t)p * OPAD + o) = s;
            }
        }
    }
}

// ---------------- fat-table fused deformable layer (L4, r12 config) ----------------
template<int C, int OREAL, int OPAD, int H, int W, int OH, int OW, int S, int MTILE>
__global__ __launch_bounds__(256, 3)
void dconv_fat(const unsigned short* __restrict__ xact,
               const unsigned short* __restrict__ wp, const float* __restrict__ bp,
               const unsigned short* __restrict__ wc,
               const float* __restrict__ g, const float* __restrict__ be,
               const float* __restrict__ m, const float* __restrict__ v,
               unsigned short* __restrict__ out)
{
    constexpr int K = C * 9;
    constexpr int KCH = C / 32;
    constexpr int OT = OPAD / 64;
    constexpr int ST = MTILE / 16;
    constexpr int PWP = MTILE / 2;
    constexpr int STP = PWP / 16;
    constexpr int CP = C + 8;
    constexpr int GL = C / 8;
    constexpr int NGRP = 256 / GL;
    constexpr int NT = MTILE / NGRP;
    constexpr int OHW = OH * OW;
    constexpr int HWC = H * W * C;
    constexpr int Hp = H + 2, Wpp = W + 2;
    static_assert(MTILE % NGRP == 0 && OPAD % 64 == 0, "tiling");

    __shared__ __align__(16) unsigned short xo[2][MTILE * CP];
    __shared__ __align__(16) i4v tab_i[MTILE][9];
    __shared__ __align__(16) f4  tab_w[MTILE][9];
    __shared__ int tab_o[MTILE][9];
    __shared__ int tab_m[MTILE][9];
    __shared__ float off_lds[MTILE][20];
    __shared__ int imgb[MTILE];
    __shared__ float scb[OPAD], shb[OPAD];

    const int tid = threadIdx.x;
    const int p0 = blockIdx.x * MTILE;

    if (tid < MTILE) imgb[tid] = ((p0 + tid) / OHW) * HWC;
    for (int o = tid; o < OREAL; o += 256) {
        float sc = g[o] * rsqrtf(v[o] + BN_EPS);
        scb[o] = sc;
        shb[o] = be[o] - m[o] * sc;
    }
    for (int e = tid; e < MTILE * 9; e += 256) {
        int lp = e / 9, n = e % 9;
        int p = p0 + lp;
        int rem = p % OHW;
        int i = rem / OW, j = rem % OW;
        int u = i * S - 1 + n / 3, vv = j * S - 1 + n % 3;
        bool ok = (u >= 0 && u < H && vv >= 0 && vv < W);
        tab_o[lp][n] = ok ? (u * W + vv) * C : 0;
        tab_m[lp][n] = ok ? -1 : 0;
    }
    __syncthreads();

    const int gl = tid % GL, grp = tid / GL;
    const int wid = tid >> 6, lane = tid & 63, quad = lane >> 4, m16 = lane & 15;

    // ---- Phase A ----
    {
        const int ogp = wid & 1, pgp = wid >> 1;
        const int obp = ogp * 16;
        const int pbp = pgp * PWP;
        i4v Tp[NT];
        auto issueA = [&](int n) {
            #pragma unroll
            for (int it = 0; it < NT; ++it) {
                const int pix = it * NGRP + grp;
                Tp[it] = *(const i4v*)(xact + imgb[pix] + gl * 8 + tab_o[pix][n]);
            }
        };
        auto commitA = [&](int n, int buf) {
            #pragma unroll
            for (int it = 0; it < NT; ++it) {
                const int pix = it * NGRP + grp;
                int mask = tab_m[pix][n];
                i4v R;
                #pragma unroll
                for (int e2 = 0; e2 < 4; ++e2) R[e2] = Tp[it][e2] & mask;
                *(i4v*)&xo[buf][pix * CP + gl * 8] = R;
            }
        };
        auto loadWp = [&](int n, short8* wf) {
            #pragma unroll
            for (int ch = 0; ch < KCH; ++ch)
                wf[ch] = *(const short8*)(wp + (size_t)(obp + m16) * K
                                          + n * C + ch * 32 + quad * 8);
        };
        f32x4 accp[STP];
        #pragma unroll
        for (int st = 0; st < STP; ++st) accp[st] = (f32x4){0.f, 0.f, 0.f, 0.f};
        short8 wfA[KCH], wfB[KCH];
        issueA(0);
        loadWp(0, wfA);
        commitA(0, 0);
        __syncthreads();
        for (int n = 0; n < 9; ++n) {
            const int cur = n & 1;
            if (n < 8) { issueA(n + 1); loadWp(n + 1, wfB); }
            #pragma unroll
            for (int ch = 0; ch < KCH; ++ch)
                #pragma unroll
                for (int st = 0; st < STP; ++st) {
                    short8 bf = *(const short8*)&xo[cur][(pbp + st * 16 + m16) * CP
                                                        + ch * 32 + quad * 8];
                    accp[st] = __builtin_amdgcn_mfma_f32_16x16x32_bf16(
                        wfA[ch], bf, accp[st], 0, 0, 0);
                }
            if (n < 8) {
                commitA(n + 1, cur ^ 1);
                #pragma unroll
                for (int ch = 0; ch < KCH; ++ch) wfA[ch] = wfB[ch];
            }
            __syncthreads();
        }
        #pragma unroll
        for (int st = 0; st < STP; ++st) {
            int pix = pbp + st * 16 + m16;
            #pragma unroll
            for (int rr = 0; rr < 4; ++rr) {
                int o = obp + quad * 4 + rr;
                if (o < 18) off_lds[pix][o] = accp[st][rr] + bp[o];
            }
        }
    }
    __syncthreads();

    // ---- Phase B ----
    for (int e = tid; e < MTILE * 9; e += 256) {
        int lp = e / 9, n = e % 9;
        int p = p0 + lp;
        int rem = p % OHW;
        int i = rem / OW, j = rem % OW;
        float ox = off_lds[lp][n];
        float oy = off_lds[lp][9 + n];
        float px = (float)(i * S + n / 3) + ox;
        float py = (float)(j * S + n % 3) + oy;
        int qx0 = (int)floorf(px), qy0 = (int)floorf(py);
        int x0 = min(max(qx0, 0), Hp - 1), x1 = min(max(qx0 + 1, 0), Hp - 1);
        int y0 = min(max(qy0, 0), Wpp - 1), y1 = min(max(qy0 + 1, 0), Wpp - 1);
        float pxc = fminf(fmaxf(px, 0.f), (float)(Hp - 1));
        float pyc = fminf(fmaxf(py, 0.f), (float)(Wpp - 1));
        float gx0 = 1.f + ((float)x0 - pxc), gx1 = 1.f - ((float)x1 - pxc);
        float gy0 = 1.f + ((float)y0 - pyc), gy1 = 1.f - ((float)y1 - pyc);
        int u0 = x0 - 1, u1 = x1 - 1, v0 = y0 - 1, v1 = y1 - 1;
        bool k0 = (u0 >= 0 && u0 < H && v0 >= 0 && v0 < W);
        bool k1 = (u1 >= 0 && u1 < H && v1 >= 0 && v1 < W);
        bool k2 = (u0 >= 0 && u0 < H && v1 >= 0 && v1 < W);
        bool k3 = (u1 >= 0 && u1 < H && v0 >= 0 && v0 < W);
        i4v ti; f4 tw;
        ti[0] = k0 ? (u0 * W + v0) * C : 0;  tw[0] = k0 ? gx0 * gy0 : 0.f;
        ti[1] = k1 ? (u1 * W + v1) * C : 0;  tw[1] = k1 ? gx1 * gy1 : 0.f;
        ti[2] = k2 ? (u0 * W + v1) * C : 0;  tw[2] = k2 ? gx0 * gy1 : 0.f;
        ti[3] = k3 ? (u1 * W + v0) * C : 0;  tw[3] = k3 ? gx1 * gy0 : 0.f;
        tab_i[lp][n] = ti;
        tab_w[lp][n] = tw;
    }
    __syncthreads();

    // ---- Phase C ----
    {
        const int obase = wid * OT * 16;
        i4v T[NT][4];
        auto issueC = [&](int n) {
            #pragma unroll
            for (int it = 0; it < NT; ++it) {
                const int pix = it * NGRP + grp;
                const unsigned short* xb = xact + imgb[pix] + gl * 8;
                i4v ti = tab_i[pix][n];
                T[it][0] = *(const i4v*)(xb + ti[0]);
                T[it][1] = *(const i4v*)(xb + ti[1]);
                T[it][2] = *(const i4v*)(xb + ti[2]);
                T[it][3] = *(const i4v*)(xb + ti[3]);
            }
        };
        auto commitC = [&](int n, int buf) {
            #pragma unroll
            for (int it = 0; it < NT; ++it) {
                const int pix = it * NGRP + grp;
                f4 tw = tab_w[pix][n];
                i4v R;
                #pragma unroll
                for (int e2 = 0; e2 < 4; ++e2) {
                    float lo = tw[0] * blo(T[it][0][e2]);
                    lo = fmaf(tw[1], blo(T[it][1][e2]), lo);
                    lo = fmaf(tw[2], blo(T[it][2][e2]), lo);
                    lo = fmaf(tw[3], blo(T[it][3][e2]), lo);
                    float hi = tw[0] * bhi(T[it][0][e2]);
                    hi = fmaf(tw[1], bhi(T[it][1][e2]), hi);
                    hi = fmaf(tw[2], bhi(T[it][2][e2]), hi);
                    hi = fmaf(tw[3], bhi(T[it][3][e2]), hi);
                    R[e2] = pkbf_fast(hi, lo);
                }
                *(i4v*)&xo[buf][pix * CP + gl * 8] = R;
            }
        };
        auto loadWc = [&](int n, short8 (*wf)[OT]) {
            #pragma unroll
            for (int ch = 0; ch < KCH; ++ch)
                #pragma unroll
                for (int t = 0; t < OT; ++t)
                    wf[ch][t] = *(const short8*)(wc + (size_t)(obase + t * 16 + m16) * K
                                                 + n * C + ch * 32 + quad * 8);
        };

        f32x4 acc[ST][OT];
        #pragma unroll
        for (int st = 0; st < ST; ++st)
            #pragma unroll
            for (int t = 0; t < OT; ++t) acc[st][t] = (f32x4){0.f, 0.f, 0.f, 0.f};

        short8 wfA[KCH][OT], wfB[KCH][OT];
        issueC(0);
        loadWc(0, wfA);
        commitC(0, 0);
        __syncthreads();

        for (int n = 0; n < 9; ++n) {
            const int cur = n & 1;
            if (n < 8) {
                issueC(n + 1);
                loadWc(n + 1, wfB);
            }
            #pragma unroll
            for (int ch = 0; ch < KCH; ++ch)
                #pragma unroll
                for (int st = 0; st < ST; ++st) {
                    short8 bf = *(const short8*)&xo[cur][(st * 16 + m16) * CP
                                                        + ch * 32 + quad * 8];
                    #pragma unroll
                    for (int t = 0; t < OT; ++t)
                        acc[st][t] = __builtin_amdgcn_mfma_f32_16x16x32_bf16(
                            wfA[ch][t], bf, acc[st][t], 0, 0, 0);
                }
            if (n < 8) {
                commitC(n + 1, cur ^ 1);
                #pragma unroll
                for (int ch = 0; ch < KCH; ++ch)
                    #pragma unroll
                    for (int t = 0; t < OT; ++t) wfA[ch][t] = wfB[ch][t];
            }
            __syncthreads();
        }

        #pragma unroll
        for (int st = 0; st < ST; ++st) {
            const int p = p0 + st * 16 + m16;
            #pragma unroll
            for (int t = 0; t < OT; ++t) {
                int o = obase + t * 16 + quad * 4;
                ushort4 s;
                #pragma unroll
                for (int rr = 0; rr < 4; ++rr)
                    ((unsigned short*)&s)[rr] =
                        f2bf(fmaxf(fmaf(acc[st][t][rr], scb[o + rr], shb[o + rr]), 0.f));
                *(ushort4*)(out + (size_t)p * OPAD + o) = s;
            }
        }
    }
}

// ---------------- global avg pool (8x8, NHWC bf16) + FC 128->100 ----------------
__global__ __launch_bounds__(128)
void pool_fc(const unsigned short* __restrict__ h4, const float* __restrict__ wcls,
             const float* __restrict__ bcls, float* __restrict__ out)
{
    __shared__ float pool[128];
    int b = blockIdx.x;
    int tid = threadIdx.x;
    const unsigned short* src = h4 + (size_t)b * 8192;
    float s = 0.f;
    #pragma unroll
    for (int t = 0; t < 64; ++t)
        s += __builtin_bit_cast(float, (unsigned)src[t * 128 + tid] << 16);
    pool[tid] = s * (1.f / 64.f);
    __syncthreads();
    if (tid < 100) {
        float acc = bcls[tid];
        const float* wr = wcls + tid * 128;
        #pragma unroll
        for (int c = 0; c < 128; ++c) acc = fmaf(pool[c], wr[c], acc);
        out[(size_t)b * 100 + tid] = acc;
    }
}

extern "C" void kernel_launch(void* const* d_in, const int* in_sizes, int n_in,
                              void* d_out, int out_size, void* d_ws, size_t ws_size,
                              hipStream_t stream)
{
    const float* x    = (const float*)d_in[0];
    const float* w1   = (const float*)d_in[1];
    const float* b1   = (const float*)d_in[2];
    const float* g1   = (const float*)d_in[3];
    const float* be1  = (const float*)d_in[4];
    const float* m1   = (const float*)d_in[5];
    const float* v1   = (const float*)d_in[6];
    const float* wp2  = (const float*)d_in[7];
    const float* bp2  = (const float*)d_in[8];
    const float* wc2  = (const float*)d_in[9];
    const float* g2   = (const float*)d_in[10];
    const float* be2  = (const float*)d_in[11];
    const float* m2   = (const float*)d_in[12];
    const float* v2   = (const float*)d_in[13];
    const float* wp3  = (const float*)d_in[14];
    const float* bp3  = (const float*)d_in[15];
    const float* wc3  = (const float*)d_in[16];
    const float* g3   = (const float*)d_in[17];
    const float* be3  = (const float*)d_in[18];
    const float* m3   = (const float*)d_in[19];
    const float* v3   = (const float*)d_in[20];
    const float* wp4  = (const float*)d_in[21];
    const float* bp4  = (const float*)d_in[22];
    const float* wc4  = (const float*)d_in[23];
    const float* g4   = (const float*)d_in[24];
    const float* be4  = (const float*)d_in[25];
    const float* m4   = (const float*)d_in[26];
    const float* v4   = (const float*)d_in[27];
    const float* wcls = (const float*)d_in[28];
    const float* bcls = (const float*)d_in[29];
    float* out = (float*)d_out;

    unsigned short* h1 = (unsigned short*)d_ws;    // NHWC bf16 256*1024*32
    unsigned short* h2 = h1 + 8388608;             // 256*256*64
    unsigned short* h3 = h2 + 4194304;             // 256*256*128
    unsigned short* h4 = h3 + 8388608;             // 256*64*128
    unsigned short* wc2b = h4 + 2097152;           // 64*288
    unsigned short* wc3b = wc2b + 18432;           // 128*576
    unsigned short* wc4b = wc3b + 73728;           // 128*1152
    unsigned short* wp2b = wc4b + 147456;          // 32*288
    unsigned short* wp3b = wp2b + 9216;            // 32*576
    unsigned short* wp4b = wp3b + 18432;           // 32*1152
    unsigned short* wq1  = wp4b + 36864;           // 32*32
    (void)ws_size; (void)in_sizes; (void)n_in; (void)out_size;

    CvtArgs ca;
    ca.s[0] = { wc2, wc2b, 64, 32, 288, 18432 };
    ca.s[1] = { wc3, wc3b, 128, 64, 576, 92160 };
    ca.s[2] = { wc4, wc4b, 128, 128, 1152, 239616 };
    ca.s[3] = { wp2, wp2b, 18, 32, 288, 248832 };
    ca.s[4] = { wp3, wp3b, 18, 64, 576, 267264 };
    ca.s[5] = { wp4, wp4b, 18, 128, 1152, 304128 };
    ca.s[6] = { w1, wq1, 32, 3, 32, 305152 };
    cvt_all<<<1192, 256, 0, stream>>>(ca);

    // Layer 1
    conv1_tile<<<1024, 256, 0, stream>>>(x, wq1, b1, g1, be1, m1, v1, h1);

    // Layer 2 (slim tables): 32x32 -> 16x16, stride 2, C=32 -> O=64
    dconv_slim<32, 64, 64, 32, 32, 16, 16, 2, 64><<<1024, 256, 0, stream>>>(
        h1, wp2b, bp2, wc2b, g2, be2, m2, v2, h2);

    // Layer 3 (slim tables): 16x16 -> 16x16, stride 1, C=64 -> O=128
    dconv_slim<64, 128, 128, 16, 16, 16, 16, 1, 64><<<1024, 256, 0, stream>>>(
        h2, wp3b, bp3, wc3b, g3, be3, m3, v3, h3);

    // Layer 4 (fat tables, r12 config): 16x16 -> 8x8, stride 2, C=128 -> O=128
    dconv_fat<128, 128, 128, 16, 16, 8, 8, 2, 32><<<512, 256, 0, stream>>>(
        h3, wp4b, bp4, wc4b, g4, be4, m4, v4, h4);

    // Pool + FC
    pool_fc<<<256, 128, 0, stream>>>(h4, wcls, bcls, out);
}